// Round 1
// baseline (153.928 us; speedup 1.0000x reference)
//
#include <hip/hip_runtime.h>

// RegionPartitioner: x (8,4,500,500) f32, step=32, region=64, edge-pad to 512.
// Out: (8, 225, 4, 64, 64) f32.  out[b,r,c,rr,rc] = x[b,c,min(32*(r/15)+rr,499),
//                                                      min(32*(r%15)+rc,499)]
//
// R2 changes vs R1 (one block per region, 256 thr x 4 float4 iters):
//  - XCD-aware block swizzle: grid 7200 = 8 XCDs x 900. swz=(bx&7)*900+(bx>>3)
//    gives XCD k the 900 contiguous logical blocks of batch k -> its read
//    working set is exactly 4 planes = 4 MB = one XCD L2. The 3.69x overlapped
//    re-reads become L2 hits instead of L3 round-trips.
//  - Non-temporal float4 stores: output is write-once/never-re-read; nt keeps
//    the 118 MB write stream from evicting the input tile out of L2.
//  - All 4 loads issued before any store (explicit v[4], constant-indexed) for
//    4-deep MLP.
// Row stride = 500 floats = 2000 B = 125*16 B, so every row start is
// 16B-aligned and the 4-wide read is ONE aligned float4 load when
// colbase <= 496. colbase >= 500 (tj==14, rc4 >= 13) is fully edge-clamped ->
// scalar load of col 499, splat. All (b,r,c,ti,tj) math is wave-uniform.

#define NB 8
#define NC 4
#define HW 500
#define RS 64
#define NT 15            // region starts per dim: 0,32,...,448
#define NREG (NT * NT)   // 225
#define NXCD 8
#define GRID (NB * NREG * NC)   // 7200
#define CPX (GRID / NXCD)       // 900 contiguous logical blocks per XCD

typedef float f32x4 __attribute__((ext_vector_type(4)));

__global__ __launch_bounds__(256) void region_partition_kernel(
    const float* __restrict__ x, float* __restrict__ out) {
    // XCD swizzle: hardware assigns consecutive blockIdx round-robin across
    // the 8 XCDs; remap so XCD (bx&7) walks a contiguous 900-block chunk.
    int bx0 = blockIdx.x;
    int bx  = (bx0 & (NXCD - 1)) * CPX + (bx0 >> 3);

    int c  = bx & 3;
    int br = bx >> 2;                // b*225 + r
    int b  = br / NREG;
    int r  = br - b * NREG;
    int ti = r / NT;
    int tj = r - ti * NT;

    int tid = threadIdx.x;
    int rc4 = tid & 15;              // float4 chunk within 64-wide row
    int rr0 = tid >> 4;              // 0..15

    int colbase = tj * 32 + rc4 * 4; // multiple of 4; <=496 or >=500
    const float* plane = x + (size_t)(b * NC + c) * (HW * HW);
    f32x4* dst = reinterpret_cast<f32x4*>(out)
               + (size_t)((b * NREG + r) * NC + c) * (RS * RS / 4);

    const bool clean = (colbase + 3 < HW);

    f32x4 v[4];                      // constant-indexed only -> stays in VGPRs
    #pragma unroll
    for (int i = 0; i < 4; ++i) {
        int rr  = rr0 + 16 * i;
        int row = min(ti * 32 + rr, HW - 1);   // edge pad (replicate last row)
        const float* src = plane + (size_t)row * HW;
        if (clean) {
            v[i] = *reinterpret_cast<const f32x4*>(src + colbase);
        } else {
            float s = src[HW - 1];             // cols 500..511 all clamp to 499
            v[i] = (f32x4){s, s, s, s};
        }
    }

    #pragma unroll
    for (int i = 0; i < 4; ++i) {
        int rr = rr0 + 16 * i;
        // nt store: don't allocate the write-once output in L2.
        __builtin_nontemporal_store(v[i], dst + rr * 16 + rc4);
    }
}

extern "C" void kernel_launch(void* const* d_in, const int* in_sizes, int n_in,
                              void* d_out, int out_size, void* d_ws, size_t ws_size,
                              hipStream_t stream) {
    const float* x = (const float*)d_in[0];
    float* out = (float*)d_out;

    region_partition_kernel<<<GRID, 256, 0, stream>>>(x, out);
}